// Round 1
// baseline (152.737 us; speedup 1.0000x reference)
//
#include <hip/hip_runtime.h>
#include <hip/hip_bf16.h>
#include <stdint.h>

#define N_ROWS 8192
#define DIM    512
#define NCENT  1000
#define BM     128
#define BK     64

typedef float  f32x4  __attribute__((ext_vector_type(4)));
typedef __bf16 bf16x8 __attribute__((ext_vector_type(8)));

__device__ __forceinline__ unsigned short f32_to_bf16_rne(float x) {
    unsigned u = __float_as_uint(x);
    u += 0x7fff + ((u >> 16) & 1);
    return (unsigned short)(u >> 16);
}

// ---------------- normalize centers (fp32) ----------------
__global__ __launch_bounds__(256) void k_norm_centers(const float* __restrict__ centers,
                                                      float* __restrict__ c_norm) {
    const int row = blockIdx.x;
    const int t = threadIdx.x;
    const float* src = centers + (size_t)row * DIM;
    float v0 = src[t], v1 = src[t + 256];
    float ss = v0 * v0 + v1 * v1;
#pragma unroll
    for (int m = 1; m < 64; m <<= 1) ss += __shfl_xor(ss, m, 64);
    __shared__ float red[4];
    const int lane = t & 63, wid = t >> 6;
    if (lane == 0) red[wid] = ss;
    __syncthreads();
    const float tot = red[0] + red[1] + red[2] + red[3];
    const float scale = 1.0f / fmaxf(sqrtf(tot), 1e-12f);
    float* dst = c_norm + (size_t)row * DIM;
    dst[t] = v0 * scale;
    dst[t + 256] = v1 * scale;
}

// ------- normalize features -> bf16, and posdot = f_i . c_label (fp32) -------
__global__ __launch_bounds__(256) void k_norm_feat(const float* __restrict__ feats,
                                                   const float* __restrict__ c_norm,
                                                   const int* __restrict__ labels,
                                                   unsigned short* __restrict__ f_bf,
                                                   float* __restrict__ posdot) {
    const int row = blockIdx.x;
    const int t = threadIdx.x;
    const float* src = feats + (size_t)row * DIM;
    float v0 = src[t], v1 = src[t + 256];
    float ss = v0 * v0 + v1 * v1;
#pragma unroll
    for (int m = 1; m < 64; m <<= 1) ss += __shfl_xor(ss, m, 64);
    __shared__ float red[8];
    const int lane = t & 63, wid = t >> 6;
    if (lane == 0) red[wid] = ss;
    __syncthreads();
    const float tot = red[0] + red[1] + red[2] + red[3];
    const float scale = 1.0f / fmaxf(sqrtf(tot), 1e-12f);
    const float n0 = v0 * scale, n1 = v1 * scale;
    f_bf[(size_t)row * DIM + t]       = f32_to_bf16_rne(n0);
    f_bf[(size_t)row * DIM + t + 256] = f32_to_bf16_rne(n1);

    const int lab = labels[row];
    const float* c = c_norm + (size_t)lab * DIM;
    float d = n0 * c[t] + n1 * c[t + 256];
#pragma unroll
    for (int m = 1; m < 64; m <<= 1) d += __shfl_xor(d, m, 64);
    if (lane == 0) red[4 + wid] = d;
    __syncthreads();
    if (t == 0) posdot[row] = red[4] + red[5] + red[6] + red[7];
}

// ---------------- fused A*A^T GEMM + masked row-reduction ----------------
// 128x128 tile, 4 waves (2x2 of 64x64), BK=64, 16x16x32 bf16 MFMA.
// LDS layout st-swizzled: phys(r,c16) = r*128 + ((c16 ^ (r&7))*16) bytes.
// global_load_lds writes linearly, so the SOURCE address carries the inverse swizzle.
__global__ __launch_bounds__(256) void k_pair(const unsigned short* __restrict__ f_bf,
                                              const int* __restrict__ labels,
                                              const float* __restrict__ pd,
                                              float* __restrict__ Ssum,
                                              int* __restrict__ Kcnt) {
    __shared__ __align__(16) unsigned char sA[BM * BK * 2];
    __shared__ __align__(16) unsigned char sB[BM * BK * 2];
    __shared__ int   s_lr[BM];
    __shared__ int   s_lc[BM];
    __shared__ float s_pd[BM];

    const int tid  = threadIdx.x;
    const int lane = tid & 63;
    const int wid  = tid >> 6;
    const int wr   = wid >> 1, wc = wid & 1;
    const int rowBase = blockIdx.x * BM;
    const int colBase = blockIdx.y * BM;

    if (tid < BM) {
        s_lr[tid] = labels[rowBase + tid];
        s_pd[tid] = pd[rowBase + tid];
    } else {
        s_lc[tid - BM] = labels[colBase + tid - BM];
    }

    f32x4 acc[4][4] = {};

    // staging geometry: each wave stages 4 chunks of 1KB for sA and sB.
    // chunk ch covers rows ch*8 .. ch*8+7; lane -> (row = ch*8 + lane>>3, phys col16 = lane&7)
    const int srow = lane >> 3;              // row within chunk, == (r & 7)
    const int sc16 = (lane & 7) ^ srow;      // logical col16 to fetch (inverse swizzle)

    for (int kt = 0; kt < DIM / BK; ++kt) {
        const int k0 = kt * BK;
        __syncthreads();  // previous tile's compute done
#pragma unroll
        for (int i = 0; i < 4; ++i) {
            const int ch = wid * 4 + i;
            const int r  = ch * 8 + srow;
            const unsigned short* gA = f_bf + ((size_t)(rowBase + r) * DIM + k0 + sc16 * 8);
            const unsigned short* gB = f_bf + ((size_t)(colBase + r) * DIM + k0 + sc16 * 8);
            __builtin_amdgcn_global_load_lds(
                (const __attribute__((address_space(1))) void*)gA,
                (__attribute__((address_space(3))) void*)(sA + ch * 1024), 16, 0, 0);
            __builtin_amdgcn_global_load_lds(
                (const __attribute__((address_space(1))) void*)gB,
                (__attribute__((address_space(3))) void*)(sB + ch * 1024), 16, 0, 0);
        }
        __syncthreads();  // staging visible

#pragma unroll
        for (int kk = 0; kk < 2; ++kk) {
            bf16x8 aF[4], bF[4];
#pragma unroll
            for (int m = 0; m < 4; ++m) {
                const int r = wr * 64 + m * 16 + (lane & 15);
                const int c16 = (kk * 4 + (lane >> 4)) ^ (r & 7);
                aF[m] = *(const bf16x8*)(sA + r * 128 + c16 * 16);
            }
#pragma unroll
            for (int n = 0; n < 4; ++n) {
                const int r = wc * 64 + n * 16 + (lane & 15);
                const int c16 = (kk * 4 + (lane >> 4)) ^ (r & 7);
                bF[n] = *(const bf16x8*)(sB + r * 128 + c16 * 16);
            }
#pragma unroll
            for (int m = 0; m < 4; ++m)
#pragma unroll
                for (int n = 0; n < 4; ++n)
                    acc[m][n] = __builtin_amdgcn_mfma_f32_16x16x32_bf16(aF[m], bF[n], acc[m][n], 0, 0, 0);
        }
    }

    // ---- masked per-row reduction epilogue ----
    // C/D layout: col = lane&15, row = (lane>>4)*4 + g  (per 16x16 fragment)
#pragma unroll
    for (int m = 0; m < 4; ++m) {
        float contrib[4] = {0.f, 0.f, 0.f, 0.f};
        int   cnt[4]     = {0, 0, 0, 0};
        const int rbase = wr * 64 + m * 16 + ((lane >> 4) << 2);
        int myLr[4]; float myPd[4];
#pragma unroll
        for (int g = 0; g < 4; ++g) { myLr[g] = s_lr[rbase + g]; myPd[g] = s_pd[rbase + g]; }
#pragma unroll
        for (int n = 0; n < 4; ++n) {
            const int jl = wc * 64 + n * 16 + (lane & 15);
            const int lc = s_lc[jl];
#pragma unroll
            for (int g = 0; g < 4; ++g) {
                const float s = acc[m][n][g];
                const bool v = (myLr[g] != lc) && (s > myPd[g]);
                if (v) { contrib[g] += (s - myPd[g]); cnt[g] += 1; }
            }
        }
#pragma unroll
        for (int g = 0; g < 4; ++g) {
#pragma unroll
            for (int d = 1; d < 16; d <<= 1) {
                contrib[g] += __shfl_xor(contrib[g], d, 64);
                cnt[g]     += __shfl_xor(cnt[g], d, 64);
            }
        }
        if ((lane & 15) == 0) {
#pragma unroll
            for (int g = 0; g < 4; ++g) {
                const int r = rowBase + rbase + g;
                atomicAdd(&Ssum[r], contrib[g]);
                atomicAdd(&Kcnt[r], cnt[g]);
            }
        }
    }
}

// ---------------- final scalar reduction ----------------
__global__ __launch_bounds__(256) void k_final(const float* __restrict__ Ssum,
                                               const int* __restrict__ Kcnt,
                                               float* __restrict__ out) {
    const int t = threadIdx.x;
    double sum = 0.0; int cnt = 0;
    for (int i = t; i < N_ROWS; i += 256) {
        const int k = Kcnt[i];
        if (k > 0) { sum += (double)Ssum[i] / (double)k; cnt += 1; }
    }
#pragma unroll
    for (int d = 1; d < 64; d <<= 1) {
        sum += __shfl_xor(sum, d, 64);
        cnt += __shfl_xor(cnt, d, 64);
    }
    __shared__ double s_sum[4];
    __shared__ int    s_cnt[4];
    const int lane = t & 63, wid = t >> 6;
    if (lane == 0) { s_sum[wid] = sum; s_cnt[wid] = cnt; }
    __syncthreads();
    if (t == 0) {
        const double ts = s_sum[0] + s_sum[1] + s_sum[2] + s_sum[3];
        const int    tc = s_cnt[0] + s_cnt[1] + s_cnt[2] + s_cnt[3];
        out[0] = (float)(tc > 0 ? ts / (double)tc : ts);
    }
}

extern "C" void kernel_launch(void* const* d_in, const int* in_sizes, int n_in,
                              void* d_out, int out_size, void* d_ws, size_t ws_size,
                              hipStream_t stream) {
    const float* features = (const float*)d_in[0];
    const float* centers  = (const float*)d_in[1];
    const int*   labels   = (const int*)d_in[2];
    float* out = (float*)d_out;

    char* ws = (char*)d_ws;
    float*          c_norm = (float*)(ws);                        // 2,048,000 B
    unsigned short* f_bf   = (unsigned short*)(ws + 0x200000);    // 8,388,608 B
    float*          posdot = (float*)(ws + 0x200000 + 0x800000);  // 32,768 B
    float*          Ssum   = (float*)(ws + 0x200000 + 0x800000 + 0x8000);
    int*            Kcnt   = (int*)  (ws + 0x200000 + 0x800000 + 0x10000);

    hipMemsetAsync(Ssum, 0, N_ROWS * sizeof(float), stream);
    hipMemsetAsync(Kcnt, 0, N_ROWS * sizeof(int), stream);

    k_norm_centers<<<NCENT, 256, 0, stream>>>(centers, c_norm);
    k_norm_feat<<<N_ROWS, 256, 0, stream>>>(features, c_norm, labels, f_bf, posdot);

    dim3 grid(N_ROWS / BM, N_ROWS / BM);
    k_pair<<<grid, 256, 0, stream>>>(f_bf, labels, posdot, Ssum, Kcnt);

    k_final<<<1, 256, 0, stream>>>(Ssum, Kcnt, out);
}

// Round 2
// 135.936 us; speedup vs baseline: 1.1236x; 1.1236x over previous
//
#include <hip/hip_runtime.h>
#include <hip/hip_bf16.h>
#include <stdint.h>
#include <math.h>

#define N_ROWS 8192
#define DIM    512
#define NCENT  1000
#define BM     128
#define BK     64
#define NB     (N_ROWS / BM)          // 64 block-rows
#define NTRI   (NB * (NB + 1) / 2)    // 2080 triangle tiles

typedef float  f32x4  __attribute__((ext_vector_type(4)));
typedef __bf16 bf16x8 __attribute__((ext_vector_type(8)));

__device__ __forceinline__ unsigned short f32_to_bf16_rne(float x) {
    unsigned u = __float_as_uint(x);
    u += 0x7fff + ((u >> 16) & 1);
    return (unsigned short)(u >> 16);
}

// ---------------- normalize centers (fp32) ----------------
__global__ __launch_bounds__(256) void k_norm_centers(const float* __restrict__ centers,
                                                      float* __restrict__ c_norm) {
    const int row = blockIdx.x;
    const int t = threadIdx.x;
    const float* src = centers + (size_t)row * DIM;
    float v0 = src[t], v1 = src[t + 256];
    float ss = v0 * v0 + v1 * v1;
#pragma unroll
    for (int m = 1; m < 64; m <<= 1) ss += __shfl_xor(ss, m, 64);
    __shared__ float red[4];
    const int lane = t & 63, wid = t >> 6;
    if (lane == 0) red[wid] = ss;
    __syncthreads();
    const float tot = red[0] + red[1] + red[2] + red[3];
    const float scale = 1.0f / fmaxf(sqrtf(tot), 1e-12f);
    float* dst = c_norm + (size_t)row * DIM;
    dst[t] = v0 * scale;
    dst[t + 256] = v1 * scale;
}

// ------- normalize features -> bf16, posdot = f_i . c_label, zero S/K -------
__global__ __launch_bounds__(256) void k_norm_feat(const float* __restrict__ feats,
                                                   const float* __restrict__ c_norm,
                                                   const int* __restrict__ labels,
                                                   unsigned short* __restrict__ f_bf,
                                                   float* __restrict__ posdot,
                                                   float* __restrict__ Ssum,
                                                   int* __restrict__ Kcnt) {
    const int row = blockIdx.x;
    const int t = threadIdx.x;
    const float* src = feats + (size_t)row * DIM;
    float v0 = src[t], v1 = src[t + 256];
    float ss = v0 * v0 + v1 * v1;
#pragma unroll
    for (int m = 1; m < 64; m <<= 1) ss += __shfl_xor(ss, m, 64);
    __shared__ float red[8];
    const int lane = t & 63, wid = t >> 6;
    if (lane == 0) red[wid] = ss;
    __syncthreads();
    const float tot = red[0] + red[1] + red[2] + red[3];
    const float scale = 1.0f / fmaxf(sqrtf(tot), 1e-12f);
    const float n0 = v0 * scale, n1 = v1 * scale;
    f_bf[(size_t)row * DIM + t]       = f32_to_bf16_rne(n0);
    f_bf[(size_t)row * DIM + t + 256] = f32_to_bf16_rne(n1);

    const int lab = labels[row];
    const float* c = c_norm + (size_t)lab * DIM;
    float d = n0 * c[t] + n1 * c[t + 256];
#pragma unroll
    for (int m = 1; m < 64; m <<= 1) d += __shfl_xor(d, m, 64);
    if (lane == 0) red[4 + wid] = d;
    __syncthreads();
    if (t == 0) {
        posdot[row] = red[4] + red[5] + red[6] + red[7];
        Ssum[row] = 0.0f;
        Kcnt[row] = 0;
    }
}

// ---------------- fused triangular A*A^T GEMM + masked row/col reduction ------
// Only upper-triangle tiles (bi <= bj). Off-diagonal tiles emit BOTH the row
// epilogue (rows I vs cols J, threshold p_i) and the column epilogue (rows J
// via s_ji == s_ij, threshold p_j). Diagonal tiles already hold both orders.
// LDS st-swizzled: phys(r,c16) = r*128 + ((c16 ^ (r&7))*16) bytes; the
// global_load_lds SOURCE carries the inverse swizzle (linear LDS dest).
__global__ __launch_bounds__(256) void k_pair(const unsigned short* __restrict__ f_bf,
                                              const int* __restrict__ labels,
                                              const float* __restrict__ pd,
                                              float* __restrict__ Ssum,
                                              int* __restrict__ Kcnt) {
    __shared__ __align__(16) unsigned char sA[BM * BK * 2];
    __shared__ __align__(16) unsigned char sB[BM * BK * 2];
    __shared__ int   s_lr[BM];
    __shared__ int   s_lc[BM];
    __shared__ float s_pd[BM];
    __shared__ float s_pc[BM];

    const int tid  = threadIdx.x;
    const int lane = tid & 63;
    const int wid  = tid >> 6;
    const int wr   = wid >> 1, wc = wid & 1;

    // triangle index -> (bi, bj), bi <= bj
    const int t = blockIdx.x;
    int bi = (int)floor((2.0 * NB + 1.0 - sqrt((2.0 * NB + 1.0) * (2.0 * NB + 1.0) - 8.0 * (double)t)) * 0.5);
    while (bi * NB - bi * (bi - 1) / 2 > t) --bi;
    while ((bi + 1) * NB - (bi + 1) * bi / 2 <= t) ++bi;
    const int bj = bi + (t - (bi * NB - bi * (bi - 1) / 2));
    const int rowBase = bi * BM;
    const int colBase = bj * BM;
    const bool offdiag = (bi != bj);

    if (tid < BM) {
        s_lr[tid] = labels[rowBase + tid];
        s_pd[tid] = pd[rowBase + tid];
    } else {
        s_lc[tid - BM] = labels[colBase + tid - BM];
        s_pc[tid - BM] = pd[colBase + tid - BM];
    }

    f32x4 acc[4][4] = {};

    // staging: each wave stages 4 chunks of 1KB per operand.
    // chunk ch covers rows ch*8..ch*8+7; lane -> (row = ch*8 + lane>>3, fetch col16 = (lane&7)^row7)
    const int srow = lane >> 3;
    const int sc16 = (lane & 7) ^ srow;

    for (int kt = 0; kt < DIM / BK; ++kt) {
        const int k0 = kt * BK;
        __syncthreads();
#pragma unroll
        for (int i = 0; i < 4; ++i) {
            const int ch = wid * 4 + i;
            const int r  = ch * 8 + srow;
            const unsigned short* gA = f_bf + ((size_t)(rowBase + r) * DIM + k0 + sc16 * 8);
            const unsigned short* gB = f_bf + ((size_t)(colBase + r) * DIM + k0 + sc16 * 8);
            __builtin_amdgcn_global_load_lds(
                (const __attribute__((address_space(1))) void*)gA,
                (__attribute__((address_space(3))) void*)(sA + ch * 1024), 16, 0, 0);
            __builtin_amdgcn_global_load_lds(
                (const __attribute__((address_space(1))) void*)gB,
                (__attribute__((address_space(3))) void*)(sB + ch * 1024), 16, 0, 0);
        }
        __syncthreads();

#pragma unroll
        for (int kk = 0; kk < 2; ++kk) {
            bf16x8 aF[4], bF[4];
#pragma unroll
            for (int m = 0; m < 4; ++m) {
                const int r = wr * 64 + m * 16 + (lane & 15);
                const int c16 = (kk * 4 + (lane >> 4)) ^ (r & 7);
                aF[m] = *(const bf16x8*)(sA + r * 128 + c16 * 16);
            }
#pragma unroll
            for (int n = 0; n < 4; ++n) {
                const int r = wc * 64 + n * 16 + (lane & 15);
                const int c16 = (kk * 4 + (lane >> 4)) ^ (r & 7);
                bF[n] = *(const bf16x8*)(sB + r * 128 + c16 * 16);
            }
#pragma unroll
            for (int m = 0; m < 4; ++m)
#pragma unroll
                for (int n = 0; n < 4; ++n)
                    acc[m][n] = __builtin_amdgcn_mfma_f32_16x16x32_bf16(aF[m], bF[n], acc[m][n], 0, 0, 0);
        }
    }

    // ---- masked row + column reduction epilogue ----
    // C/D layout: col = lane&15, row = (lane>>4)*4 + g (per 16x16 fragment)
    float colS[4] = {0.f, 0.f, 0.f, 0.f};
    int   colK[4] = {0, 0, 0, 0};

#pragma unroll
    for (int m = 0; m < 4; ++m) {
        float rowS[4] = {0.f, 0.f, 0.f, 0.f};
        int   rowK[4] = {0, 0, 0, 0};
        const int rbase = wr * 64 + m * 16 + ((lane >> 4) << 2);
        int myLr[4]; float myPd[4];
#pragma unroll
        for (int g = 0; g < 4; ++g) { myLr[g] = s_lr[rbase + g]; myPd[g] = s_pd[rbase + g]; }
#pragma unroll
        for (int n = 0; n < 4; ++n) {
            const int jl = wc * 64 + n * 16 + (lane & 15);
            const int lc = s_lc[jl];
            const float pc = s_pc[jl];
#pragma unroll
            for (int g = 0; g < 4; ++g) {
                const float s = acc[m][n][g];
                const bool diff = (myLr[g] != lc);
                if (diff && s > myPd[g]) { rowS[g] += (s - myPd[g]); rowK[g] += 1; }
                if (offdiag && diff && s > pc) { colS[n] += (s - pc); colK[n] += 1; }
            }
        }
#pragma unroll
        for (int g = 0; g < 4; ++g) {
#pragma unroll
            for (int d = 1; d < 16; d <<= 1) {
                rowS[g] += __shfl_xor(rowS[g], d, 64);
                rowK[g] += __shfl_xor(rowK[g], d, 64);
            }
        }
        if ((lane & 15) == 0) {
#pragma unroll
            for (int g = 0; g < 4; ++g) {
                const int r = rowBase + rbase + g;
                atomicAdd(&Ssum[r], rowS[g]);
                atomicAdd(&Kcnt[r], rowK[g]);
            }
        }
    }

    if (offdiag) {
#pragma unroll
        for (int n = 0; n < 4; ++n) {
#pragma unroll
            for (int d = 16; d < 64; d <<= 1) {
                colS[n] += __shfl_xor(colS[n], d, 64);
                colK[n] += __shfl_xor(colK[n], d, 64);
            }
        }
        if (lane < 16) {
#pragma unroll
            for (int n = 0; n < 4; ++n) {
                const int c = colBase + wc * 64 + n * 16 + lane;
                atomicAdd(&Ssum[c], colS[n]);
                atomicAdd(&Kcnt[c], colK[n]);
            }
        }
    }
}

// ---------------- final scalar reduction ----------------
__global__ __launch_bounds__(1024) void k_final(const float* __restrict__ Ssum,
                                                const int* __restrict__ Kcnt,
                                                float* __restrict__ out) {
    const int t = threadIdx.x;
    double sum = 0.0; int cnt = 0;
    for (int i = t; i < N_ROWS; i += 1024) {
        const int k = Kcnt[i];
        if (k > 0) { sum += (double)Ssum[i] / (double)k; cnt += 1; }
    }
#pragma unroll
    for (int d = 1; d < 64; d <<= 1) {
        sum += __shfl_xor(sum, d, 64);
        cnt += __shfl_xor(cnt, d, 64);
    }
    __shared__ double s_sum[16];
    __shared__ int    s_cnt[16];
    const int lane = t & 63, wid = t >> 6;
    if (lane == 0) { s_sum[wid] = sum; s_cnt[wid] = cnt; }
    __syncthreads();
    if (t == 0) {
        double ts = 0.0; int tc = 0;
#pragma unroll
        for (int w = 0; w < 16; ++w) { ts += s_sum[w]; tc += s_cnt[w]; }
        out[0] = (float)(tc > 0 ? ts / (double)tc : ts);
    }
}

extern "C" void kernel_launch(void* const* d_in, const int* in_sizes, int n_in,
                              void* d_out, int out_size, void* d_ws, size_t ws_size,
                              hipStream_t stream) {
    const float* features = (const float*)d_in[0];
    const float* centers  = (const float*)d_in[1];
    const int*   labels   = (const int*)d_in[2];
    float* out = (float*)d_out;

    char* ws = (char*)d_ws;
    float*          c_norm = (float*)(ws);                        // 2,048,000 B
    unsigned short* f_bf   = (unsigned short*)(ws + 0x200000);    // 8,388,608 B
    float*          posdot = (float*)(ws + 0x200000 + 0x800000);  // 32,768 B
    float*          Ssum   = (float*)(ws + 0x200000 + 0x800000 + 0x8000);
    int*            Kcnt   = (int*)  (ws + 0x200000 + 0x800000 + 0x10000);

    k_norm_centers<<<NCENT, 256, 0, stream>>>(centers, c_norm);
    k_norm_feat<<<N_ROWS, 256, 0, stream>>>(features, c_norm, labels, f_bf, posdot, Ssum, Kcnt);

    k_pair<<<NTRI, 256, 0, stream>>>(f_bf, labels, posdot, Ssum, Kcnt);

    k_final<<<1, 1024, 0, stream>>>(Ssum, Kcnt, out);
}